// Round 2
// baseline (846.825 us; speedup 1.0000x reference)
//
#include <hip/hip_runtime.h>
#include <math.h>

// ResGraph: B=4, N=E=100000, H=128
//   h = x @ wi                         [B,N,128]
//   d = sort(h[src] - h[dst], -1)      per edge (E==N)
//   s = sum(d @ wh, -1) == d_sorted . rowsum(wh)   <-- algebraic collapse
//   out = 0.8*h + 0.2*tanh(s + h)

#define LEAKY 0.2f

// ---------------- K0: wsum[h] = sum_k wh[h][k] ----------------
__global__ void k_wsum(const float* __restrict__ wh, float* __restrict__ wsum) {
    int hh = threadIdx.x;  // 128 threads
    float s = 0.f;
    #pragma unroll 4
    for (int k = 0; k < 128; ++k) s += wh[hh * 128 + k];
    wsum[hh] = s;
}

// ---------------- K1: h = x @ wi  (f32, tiled) ----------------
// block: 256 threads, 64 rows per block.
// thread t: col group cg = t&31 -> cols {cg, cg+32, cg+64, cg+96} (strided ->
// conflict-free b128 LDS reads of wiT), row group rg = t>>5 -> rows rg*8..+7.
__global__ __launch_bounds__(256) void k_gemm(const float* __restrict__ x,
                                              const float* __restrict__ wi,
                                              float* __restrict__ h,
                                              int total_rows) {
    __shared__ __align__(16) float wiT[128][132];  // wiT[c][d], pad 132
    __shared__ __align__(16) float xs[64][128];

    // load wi transposed (coalesced global, one-time LDS write)
    for (int i = threadIdx.x; i < 128 * 128; i += 256) {
        int d = i >> 7, c = i & 127;
        wiT[c][d] = wi[i];
    }
    int row0 = blockIdx.x * 64;
    int rows_here = total_rows - row0; if (rows_here > 64) rows_here = 64;
    {
        const float4* xg = reinterpret_cast<const float4*>(x + (size_t)row0 * 128);
        float4* xsv = reinterpret_cast<float4*>(&xs[0][0]);
        int n4 = rows_here * 32;  // float4 count
        for (int i = threadIdx.x; i < n4; i += 256) xsv[i] = xg[i];
    }
    __syncthreads();

    const int cg = threadIdx.x & 31;
    const int rg = threadIdx.x >> 5;
    const int r0 = rg * 8;

    float acc[8][4];
    #pragma unroll
    for (int r = 0; r < 8; ++r)
        #pragma unroll
        for (int j = 0; j < 4; ++j) acc[r][j] = 0.f;

    for (int d = 0; d < 128; d += 4) {
        float4 w0 = *reinterpret_cast<const float4*>(&wiT[cg +  0][d]);
        float4 w1 = *reinterpret_cast<const float4*>(&wiT[cg + 32][d]);
        float4 w2 = *reinterpret_cast<const float4*>(&wiT[cg + 64][d]);
        float4 w3 = *reinterpret_cast<const float4*>(&wiT[cg + 96][d]);
        #pragma unroll
        for (int r = 0; r < 8; ++r) {
            float4 xv = *reinterpret_cast<const float4*>(&xs[r0 + r][d]);
            acc[r][0] += xv.x * w0.x + xv.y * w0.y + xv.z * w0.z + xv.w * w0.w;
            acc[r][1] += xv.x * w1.x + xv.y * w1.y + xv.z * w1.z + xv.w * w1.w;
            acc[r][2] += xv.x * w2.x + xv.y * w2.y + xv.z * w2.z + xv.w * w2.w;
            acc[r][3] += xv.x * w3.x + xv.y * w3.y + xv.z * w3.z + xv.w * w3.w;
        }
    }

    #pragma unroll
    for (int r = 0; r < 8; ++r) {
        if (r0 + r < rows_here) {
            float* hp = h + (size_t)(row0 + r0 + r) * 128;
            hp[cg +  0] = acc[r][0];
            hp[cg + 32] = acc[r][1];
            hp[cg + 64] = acc[r][2];
            hp[cg + 96] = acc[r][3];
        }
    }
}

// ---------------- K2: per-(b,edge) gather + bitonic sort + combine ----------------
// one wave (64 lanes) per (b,n); lane holds elements i=2*lane and i=2*lane+1.
__global__ __launch_bounds__(256) void k_edge(const float* __restrict__ h,
                                              const int* __restrict__ ei,  // [2][N]
                                              const float* __restrict__ wsum,
                                              float* __restrict__ out,
                                              int Nn, int Bb) {
    const int lane = threadIdx.x & 63;
    const long long gw = (long long)blockIdx.x * 4 + (threadIdx.x >> 6);
    const long long total = (long long)Bb * Nn;
    if (gw >= total) return;
    const int b = (int)(gw / Nn);
    const int n = (int)(gw % Nn);

    const int src = ei[n];        // edge_index[0][n]
    const int dst = ei[Nn + n];   // edge_index[1][n]
    const float* hb = h + (size_t)b * Nn * 128;

    const float2 hj = *reinterpret_cast<const float2*>(hb + (size_t)src * 128 + 2 * lane);
    const float2 hi = *reinterpret_cast<const float2*>(hb + (size_t)dst * 128 + 2 * lane);
    float e0 = hj.x - hi.x;
    float e1 = hj.y - hi.y;

    // bitonic sort of 128 elements across the wave (ascending)
    #pragma unroll
    for (int k = 2; k <= 128; k <<= 1) {
        const bool asc = ((2 * lane) & k) == 0;  // uniform for both lane elems (k>=2)
        #pragma unroll
        for (int dist = k >> 1; dist >= 2; dist >>= 1) {
            const int m = dist >> 1;  // lane xor mask
            float p0 = __shfl_xor(e0, m, 64);
            float p1 = __shfl_xor(e1, m, 64);
            const bool lower = (lane & m) == 0;
            const bool keepmin = (lower == asc);
            e0 = keepmin ? fminf(e0, p0) : fmaxf(e0, p0);
            e1 = keepmin ? fminf(e1, p1) : fmaxf(e1, p1);
        }
        { // dist == 1: in-lane pair
            float lo = fminf(e0, e1), hi2 = fmaxf(e0, e1);
            e0 = asc ? lo : hi2;
            e1 = asc ? hi2 : lo;
        }
    }

    // dot with wsum, wave-reduce
    const float2 wv = *reinterpret_cast<const float2*>(wsum + 2 * lane);
    float s = e0 * wv.x + e1 * wv.y;
    #pragma unroll
    for (int m = 32; m >= 1; m >>= 1) s += __shfl_xor(s, m, 64);

    // combine + store
    const float2 hn = *reinterpret_cast<const float2*>(hb + (size_t)n * 128 + 2 * lane);
    float2 o;
    o.x = (1.f - LEAKY) * hn.x + LEAKY * tanhf(s + hn.x);
    o.y = (1.f - LEAKY) * hn.y + LEAKY * tanhf(s + hn.y);
    *reinterpret_cast<float2*>(out + ((size_t)b * Nn + n) * 128 + 2 * lane) = o;
}

extern "C" void kernel_launch(void* const* d_in, const int* in_sizes, int n_in,
                              void* d_out, int out_size, void* d_ws, size_t ws_size,
                              hipStream_t stream) {
    const float* x  = (const float*)d_in[0];
    const int*   ei = (const int*)d_in[1];
    const float* wi = (const float*)d_in[2];
    const float* wh = (const float*)d_in[3];
    float* out = (float*)d_out;

    const int N = in_sizes[1] / 2;              // 100000
    const int B = in_sizes[0] / (N * 128);      // 4
    const int total_rows = B * N;               // 400000

    float* h    = (float*)d_ws;                 // total_rows*128 floats
    float* wsum = h + (size_t)total_rows * 128; // 128 floats

    k_wsum<<<1, 128, 0, stream>>>(wh, wsum);
    k_gemm<<<(total_rows + 63) / 64, 256, 0, stream>>>(x, wi, h, total_rows);
    const long long waves = (long long)B * N;
    k_edge<<<(int)((waves + 3) / 4), 256, 0, stream>>>(h, ei, wsum, out, N, B);
}

// Round 3
// 627.501 us; speedup vs baseline: 1.3495x; 1.3495x over previous
//
#include <hip/hip_runtime.h>
#include <math.h>

// ResGraph: B=4, N=E=100000, H=128
//   h = x @ wi                         [B,N,128]
//   d = sort(h[src] - h[dst], -1)      per edge (E==N)
//   s = sum(d @ wh, -1) == d_sorted . rowsum(wh)   <-- algebraic collapse
//   out = 0.8*h + 0.2*tanh(s + h)
//
// k_gemm: split-bf16 MFMA (x=xh+xl, w=wh+wl; h = xh*wh + xh*wl + xl*wh).
// k_edge: wave-wide bitonic sort; DPP for xor1/2, ds_swizzle for xor4/8.

#define LEAKY 0.2f

typedef __attribute__((__ext_vector_type__(4))) float  f32x4;
typedef __attribute__((__ext_vector_type__(8))) short  s16x8;
typedef __attribute__((__ext_vector_type__(4))) short  s16x4;

__device__ __forceinline__ unsigned short f2bf(float f) {  // RNE f32->bf16
    unsigned u = __builtin_bit_cast(unsigned, f);
    u += 0x7FFFu + ((u >> 16) & 1u);
    return (unsigned short)(u >> 16);
}
__device__ __forceinline__ float bf2f(unsigned short s) {
    unsigned u = ((unsigned)s) << 16;
    return __builtin_bit_cast(float, u);
}

// ---------------- K0a: transpose wi -> Wb[n][k] as bf16 hi/lo ----------------
__global__ void k_wprep(const float* __restrict__ wi,
                        unsigned short* __restrict__ wbh,
                        unsigned short* __restrict__ wbl) {
    int idx = blockIdx.x * 256 + threadIdx.x;  // 0..16383
    int k = idx >> 7, n = idx & 127;
    float w = wi[idx];                 // wi[k][n]
    unsigned short hb = f2bf(w);
    unsigned short lb = f2bf(w - bf2f(hb));
    wbh[n * 128 + k] = hb;
    wbl[n * 128 + k] = lb;
}

// ---------------- K0b: wsum[h] = sum_k wh[h][k] ----------------
__global__ void k_wsum(const float* __restrict__ wh, float* __restrict__ wsum) {
    int hh = threadIdx.x;  // 128 threads
    float s = 0.f;
    #pragma unroll 4
    for (int k = 0; k < 128; ++k) s += wh[hh * 128 + k];
    wsum[hh] = s;
}

// ---------------- K1: h = x @ wi via split-bf16 MFMA ----------------
// 256 threads = 4 waves; block tile 128 rows x 128 cols, K=128 (4 ktiles of 32).
// Wave w: rows [w*32, w*32+32) as 2 m-frags; all 128 cols as 8 n-frags.
// X staged in LDS (bf16 hi/lo, XOR-swizzled 16B blocks); W frags read from
// global (prepped transposed [n][k]) -> L1-resident, LDS stays 64KB -> 2 blk/CU.
__global__ __launch_bounds__(256, 2) void k_gemm(const float* __restrict__ x,
                                                 const unsigned short* __restrict__ wbh,
                                                 const unsigned short* __restrict__ wbl,
                                                 float* __restrict__ h,
                                                 int total_rows) {
    __shared__ unsigned short Xh[128][128];
    __shared__ unsigned short Xl[128][128];
    const int tid = threadIdx.x;
    const int row0 = blockIdx.x * 128;

    // ---- stage X tile, f32 -> bf16 hi/lo, swizzled ----
    #pragma unroll
    for (int i = 0; i < 16; ++i) {
        int fi = tid + 256 * i;           // float4 index within tile (0..4095)
        int r  = fi >> 5;                 // tile row
        int c4 = fi & 31;                 // float4 col
        int grow = row0 + r; if (grow > total_rows - 1) grow = total_rows - 1;
        f32x4 v = *reinterpret_cast<const f32x4*>(x + (size_t)grow * 128 + c4 * 4);
        s16x4 hi, lo;
        #pragma unroll
        for (int j = 0; j < 4; ++j) {
            unsigned short hb = f2bf(v[j]);
            hi[j] = (short)hb;
            lo[j] = (short)f2bf(v[j] - bf2f(hb));
        }
        int c = (c4 * 4) ^ ((r & 7) << 3);  // swizzle 16B blocks, keeps 8B align
        *reinterpret_cast<s16x4*>(&Xh[r][c]) = hi;
        *reinterpret_cast<s16x4*>(&Xl[r][c]) = lo;
    }
    __syncthreads();

    const int lane = tid & 63;
    const int wm0  = (tid >> 6) * 32;
    const int lm   = lane & 15;          // m / n index within frag
    const int lk   = (lane >> 4) * 8;    // k offset within 32-k tile

    f32x4 acc[2][8];
    #pragma unroll
    for (int mt = 0; mt < 2; ++mt)
        #pragma unroll
        for (int nt = 0; nt < 8; ++nt) acc[mt][nt] = (f32x4)0.f;

    #pragma unroll
    for (int kt = 0; kt < 4; ++kt) {
        const int k0 = kt * 32 + lk;
        s16x8 ah[2], al[2];
        #pragma unroll
        for (int mt = 0; mt < 2; ++mt) {
            int r = wm0 + mt * 16 + lm;
            int c = k0 ^ ((r & 7) << 3);
            ah[mt] = *reinterpret_cast<const s16x8*>(&Xh[r][c]);
            al[mt] = *reinterpret_cast<const s16x8*>(&Xl[r][c]);
        }
        s16x8 bh[8], bl[8];
        #pragma unroll
        for (int nt = 0; nt < 8; ++nt) {
            const size_t off = (size_t)(nt * 16 + lm) * 128 + k0;
            bh[nt] = *reinterpret_cast<const s16x8*>(wbh + off);
            bl[nt] = *reinterpret_cast<const s16x8*>(wbl + off);
        }
        #pragma unroll
        for (int mt = 0; mt < 2; ++mt)
            #pragma unroll
            for (int nt = 0; nt < 8; ++nt) {
                acc[mt][nt] = __builtin_amdgcn_mfma_f32_16x16x32_bf16(al[mt], bh[nt], acc[mt][nt], 0, 0, 0);
                acc[mt][nt] = __builtin_amdgcn_mfma_f32_16x16x32_bf16(ah[mt], bl[nt], acc[mt][nt], 0, 0, 0);
                acc[mt][nt] = __builtin_amdgcn_mfma_f32_16x16x32_bf16(ah[mt], bh[nt], acc[mt][nt], 0, 0, 0);
            }
    }

    // ---- epilogue: C/D layout col=lane&15, row=(lane>>4)*4+reg ----
    const int orow = (lane >> 4) * 4;
    #pragma unroll
    for (int mt = 0; mt < 2; ++mt)
        #pragma unroll
        for (int nt = 0; nt < 8; ++nt)
            #pragma unroll
            for (int r = 0; r < 4; ++r) {
                int grow = row0 + wm0 + mt * 16 + orow + r;
                if (grow < total_rows)
                    h[(size_t)grow * 128 + nt * 16 + lm] = acc[mt][nt][r];
            }
}

// ---------------- K2: gather + bitonic sort + combine ----------------
__device__ __forceinline__ float dppx(float v, int ctl_is_1) { return v; } // unused

template <int M>
__device__ __forceinline__ float lane_xor(float v) {
    if constexpr (M == 1) {
        return __builtin_bit_cast(float, __builtin_amdgcn_update_dpp(
            0, __builtin_bit_cast(int, v), 0xB1, 0xF, 0xF, true));   // quad_perm [1,0,3,2]
    } else if constexpr (M == 2) {
        return __builtin_bit_cast(float, __builtin_amdgcn_update_dpp(
            0, __builtin_bit_cast(int, v), 0x4E, 0xF, 0xF, true));   // quad_perm [2,3,0,1]
    } else if constexpr (M == 4) {
        return __builtin_bit_cast(float, __builtin_amdgcn_ds_swizzle(
            __builtin_bit_cast(int, v), 0x101F));                    // xor 4
    } else if constexpr (M == 8) {
        return __builtin_bit_cast(float, __builtin_amdgcn_ds_swizzle(
            __builtin_bit_cast(int, v), 0x201F));                    // xor 8
    } else {
        return __shfl_xor(v, M, 64);
    }
}

__global__ __launch_bounds__(256) void k_edge(const float* __restrict__ h,
                                              const int* __restrict__ ei,  // [2][N] as int32
                                              const float* __restrict__ wsum,
                                              float* __restrict__ out,
                                              int Nn, int Bb) {
    const int lane = threadIdx.x & 63;
    const long long gw = (long long)blockIdx.x * 4 + (threadIdx.x >> 6);
    const long long total = (long long)Bb * Nn;
    if (gw >= total) return;
    const int b = (int)(gw / Nn);
    const int n = (int)(gw % Nn);

    const int src = ei[n];        // edge_index[0][n]
    const int dst = ei[Nn + n];   // edge_index[1][n]
    const float* hb = h + (size_t)b * Nn * 128;

    const float2 hj = *reinterpret_cast<const float2*>(hb + (size_t)src * 128 + 2 * lane);
    const float2 hi = *reinterpret_cast<const float2*>(hb + (size_t)dst * 128 + 2 * lane);
    float e0 = hj.x - hi.x;
    float e1 = hj.y - hi.y;

#define CE(M) { float p0 = lane_xor<M>(e0); float p1 = lane_xor<M>(e1);          \
                bool keepmin = (((lane & (M)) == 0) == asc);                      \
                e0 = keepmin ? fminf(e0, p0) : fmaxf(e0, p0);                     \
                e1 = keepmin ? fminf(e1, p1) : fmaxf(e1, p1); }
#define INLANE { float lo_ = fminf(e0, e1), hi_ = fmaxf(e0, e1);                  \
                 e0 = asc ? lo_ : hi_;  e1 = asc ? hi_ : lo_; }

    { const bool asc = ((2 * lane) &   2) == 0;                                        INLANE; }
    { const bool asc = ((2 * lane) &   4) == 0; CE(1)                                  INLANE; }
    { const bool asc = ((2 * lane) &   8) == 0; CE(2) CE(1)                            INLANE; }
    { const bool asc = ((2 * lane) &  16) == 0; CE(4) CE(2) CE(1)                      INLANE; }
    { const bool asc = ((2 * lane) &  32) == 0; CE(8) CE(4) CE(2) CE(1)                INLANE; }
    { const bool asc = ((2 * lane) &  64) == 0; CE(16) CE(8) CE(4) CE(2) CE(1)         INLANE; }
    { const bool asc = true;                    CE(32) CE(16) CE(8) CE(4) CE(2) CE(1)  INLANE; }
#undef CE
#undef INLANE

    // dot with wsum, wave-reduce (cheap pipes where possible)
    const float2 wv = *reinterpret_cast<const float2*>(wsum + 2 * lane);
    float s = e0 * wv.x + e1 * wv.y;
    s += __shfl_xor(s, 32, 64);
    s += __shfl_xor(s, 16, 64);
    s += lane_xor<8>(s);
    s += lane_xor<4>(s);
    s += lane_xor<2>(s);
    s += lane_xor<1>(s);

    const float2 hn = *reinterpret_cast<const float2*>(hb + (size_t)n * 128 + 2 * lane);
    float2 o;
    o.x = (1.f - LEAKY) * hn.x + LEAKY * tanhf(s + hn.x);
    o.y = (1.f - LEAKY) * hn.y + LEAKY * tanhf(s + hn.y);
    *reinterpret_cast<float2*>(out + ((size_t)b * Nn + n) * 128 + 2 * lane) = o;
}

extern "C" void kernel_launch(void* const* d_in, const int* in_sizes, int n_in,
                              void* d_out, int out_size, void* d_ws, size_t ws_size,
                              hipStream_t stream) {
    const float* x  = (const float*)d_in[0];
    const int*   ei = (const int*)d_in[1];
    const float* wi = (const float*)d_in[2];
    const float* wh = (const float*)d_in[3];
    float* out = (float*)d_out;

    const int N = in_sizes[1] / 2;              // 100000
    const int B = in_sizes[0] / (N * 128);      // 4
    const int total_rows = B * N;               // 400000

    float* h    = (float*)d_ws;                             // total_rows*128 f32
    float* wsum = h + (size_t)total_rows * 128;             // 128 f32
    unsigned short* wbh = (unsigned short*)(wsum + 128);    // 128*128 bf16
    unsigned short* wbl = wbh + 128 * 128;                  // 128*128 bf16

    k_wprep<<<64, 256, 0, stream>>>(wi, wbh, wbl);
    k_wsum<<<1, 128, 0, stream>>>(wh, wsum);
    k_gemm<<<(total_rows + 127) / 128, 256, 0, stream>>>(x, wbh, wbl, h, total_rows);
    const long long waves = (long long)B * N;
    k_edge<<<(int)((waves + 3) / 4), 256, 0, stream>>>(h, ei, wsum, out, N, B);
}